// Round 9
// baseline (235.283 us; speedup 1.0000x reference)
//
#include <hip/hip_runtime.h>
#include <hip/hip_bf16.h>

typedef __bf16 bf16x8 __attribute__((ext_vector_type(8)));
typedef float  f32x4  __attribute__((ext_vector_type(4)));

#define B_   4
#define N_   4096
#define FIN  300
#define FOUT 300
#define FP   320   // padded feature dim (multiple of 32)
#define MT   64    // adjb tile rows
#define KT   64    // adjb tile cols
#define NMT  (N_/MT)
#define NKT  (N_/KT)
#define TILE_BYTES (MT*KT*2)   // 8192
#define YTILE 2048             // Ytt tile: 16 f x 64 k bf16
#define STEP2 36864            // per-K-step LDS: A 16 KB + B 20 KB

// ws layout (bytes)
#define WT_OFF   0                    // Wt   bf16 [FP][FP]
#define D_OFF    (512*1024)           // d    fp32 [B_*N_]
#define TSC_OFF  (1024*1024)          // Tsc  bf16 [B_*N_][FP]
#define YT_OFF   (16*1024*1024)       // Yt / Ytt (tiled)  ~10.5 MB
#define ADJB_OFF (32*1024*1024)       // adjb bf16 tiled+swizzled [B_][NMT][NKT][8KB]
#define ADJB_BYTES ((size_t)B_ * N_ * N_ * 2)

#define SB() __builtin_amdgcn_sched_barrier(0)

__device__ __forceinline__ void gload_lds16(const void* g, void* l) {
    __builtin_amdgcn_global_load_lds((const __attribute__((address_space(1))) void*)g,
                                     (__attribute__((address_space(3))) void*)l, 16, 0, 0);
}

// ---------------- K0: Wt[f][k] = bf16(W[k][f]), zero-padded ----------------
__global__ void k_wt(const float* __restrict__ W, __bf16* __restrict__ Wt) {
    int t = blockIdx.x * 256 + threadIdx.x;
    if (t >= FP * FP) return;
    int f = t / FP, k = t - f * FP;
    float v = (f < FOUT && k < FIN) ? W[k * FOUT + f] : 0.0f;
    Wt[t] = (__bf16)v;
}

// ---------------- K1a: rowsum only (fallback path) -------------------------
__global__ void k_rowsum(const float* __restrict__ adj, float* __restrict__ d) {
    int row  = blockIdx.x * 4 + (threadIdx.x >> 6);
    int lane = threadIdx.x & 63;
    const float4* p = (const float4*)(adj + (size_t)row * N_);
    float s = 0.0f;
#pragma unroll
    for (int it = 0; it < 16; ++it) {
        float4 v = p[it * 64 + lane];
        s += v.x + v.y + v.z + v.w;
    }
#pragma unroll
    for (int off = 32; off; off >>= 1) s += __shfl_xor(s, off);
    if (lane == 0) d[row] = rsqrtf(s + 1.0f);
}

// ---------------- K1b: rowsum + tiled/swizzled bf16 copy of adj ------------
// Tile layout: adjb[(b*NMT+mt)*NKT + kt] is 8 KB = rows [mloc][64 bf16],
// with 16B chunk c stored at byte  mloc*128 + (c*16 ^ ((mloc&7)<<4)).
__global__ void k_rowsum_cvt(const float* __restrict__ adj, float* __restrict__ d,
                             char* __restrict__ adjb) {
    int g    = blockIdx.x * 4 + (threadIdx.x >> 6);   // global row 0..B_*N_-1
    int lane = threadIdx.x & 63;                      // = kt
    int b    = g >> 12;
    int row  = g & (N_ - 1);
    int mt   = row >> 6, mloc = row & 63;
    const float4* p = (const float4*)(adj + (size_t)g * N_) + lane * 16;
    float4 v[16];
#pragma unroll
    for (int i = 0; i < 16; ++i) v[i] = p[i];
    float s = 0.0f;
#pragma unroll
    for (int i = 0; i < 16; ++i) s += v[i].x + v[i].y + v[i].z + v[i].w;
    char* tb = adjb + (size_t)((b * NMT + mt) * NKT + lane) * TILE_BYTES + mloc * 128;
    int sw = (mloc & 7) << 4;
#pragma unroll
    for (int c = 0; c < 8; ++c) {
        float4 v0 = v[2 * c], v1 = v[2 * c + 1];
        bf16x8 o;
        o[0] = (__bf16)v0.x; o[1] = (__bf16)v0.y; o[2] = (__bf16)v0.z; o[3] = (__bf16)v0.w;
        o[4] = (__bf16)v1.x; o[5] = (__bf16)v1.y; o[6] = (__bf16)v1.z; o[7] = (__bf16)v1.w;
        *(bf16x8*)(tb + ((c * 16) ^ sw)) = o;
    }
#pragma unroll
    for (int off = 32; off; off >>= 1) s += __shfl_xor(s, off);
    if (lane == 0) d[g] = rsqrtf(s + 1.0f);
}

// ---------------- K2: Tsc[j][k] = bf16(d[j]*text[j][k]), K zero-padded -----
__global__ void k_tsc(const float* __restrict__ text, const float* __restrict__ d,
                      __bf16* __restrict__ Tsc) {
    int t = blockIdx.x * 256 + threadIdx.x;
    int j = t / FP;
    int k = t - j * FP;
    float v = 0.0f;
    if (k < FIN) v = d[j] * text[(size_t)j * FIN + k];
    Tsc[t] = (__bf16)v;
}

// ---------------- K3a: plain Yt (fallback): Yt[b][f][j] --------------------
__global__ __launch_bounds__(256) void k_y(const __bf16* __restrict__ Wt,
                                           const __bf16* __restrict__ Tsc,
                                           __bf16* __restrict__ Yt) {
    int b    = blockIdx.y;
    int j0   = blockIdx.x * 64;
    int wave = threadIdx.x >> 6, lane = threadIdx.x & 63;
    int lr = lane & 15, lg = lane >> 4;
    f32x4 acc[5][4] = {};
    for (int k0 = 0; k0 < FP; k0 += 32) {
        bf16x8 a[5], bb[4];
#pragma unroll
        for (int fi = 0; fi < 5; ++fi) {
            int f = (wave * 5 + fi) * 16 + lr;
            a[fi] = *(const bf16x8*)(Wt + (size_t)f * FP + k0 + lg * 8);
        }
#pragma unroll
        for (int ji = 0; ji < 4; ++ji) {
            int j = j0 + ji * 16 + lr;
            bb[ji] = *(const bf16x8*)(Tsc + ((size_t)(b * N_ + j)) * FP + k0 + lg * 8);
        }
#pragma unroll
        for (int fi = 0; fi < 5; ++fi)
#pragma unroll
            for (int ji = 0; ji < 4; ++ji)
                acc[fi][ji] = __builtin_amdgcn_mfma_f32_16x16x32_bf16(a[fi], bb[ji], acc[fi][ji], 0, 0, 0);
    }
#pragma unroll
    for (int fi = 0; fi < 5; ++fi)
#pragma unroll
        for (int ji = 0; ji < 4; ++ji)
#pragma unroll
            for (int r = 0; r < 4; ++r) {
                int f = (wave * 5 + fi) * 16 + lg * 4 + r;
                int j = j0 + ji * 16 + lr;
                Yt[((size_t)b * FP + f) * N_ + j] = (__bf16)acc[fi][ji][r];
            }
}

// ---------------- K3b: tiled+swizzled Ytt for the pipelined GEMM -----------
// Ytt tile (ft, kt): 2 KB = 16 f-rows x 64 k bf16, tile idx (b*20+ft)*64+kt.
// Within tile: row floc (=f&15) at byte floc*128; 16-B chunk c of the row at
// byte (c*16 ^ ((floc&7)<<4)); elements (k&7) consecutive inside the chunk.
__global__ __launch_bounds__(256) void k_y_t(const __bf16* __restrict__ Wt,
                                             const __bf16* __restrict__ Tsc,
                                             char* __restrict__ Ytt) {
    int b    = blockIdx.y;
    int j0   = blockIdx.x * 64;
    int wave = threadIdx.x >> 6, lane = threadIdx.x & 63;
    int lr = lane & 15, lg = lane >> 4;
    f32x4 acc[5][4] = {};
    for (int k0 = 0; k0 < FP; k0 += 32) {
        bf16x8 a[5], bb[4];
#pragma unroll
        for (int fi = 0; fi < 5; ++fi) {
            int f = (wave * 5 + fi) * 16 + lr;
            a[fi] = *(const bf16x8*)(Wt + (size_t)f * FP + k0 + lg * 8);
        }
#pragma unroll
        for (int ji = 0; ji < 4; ++ji) {
            int j = j0 + ji * 16 + lr;
            bb[ji] = *(const bf16x8*)(Tsc + ((size_t)(b * N_ + j)) * FP + k0 + lg * 8);
        }
#pragma unroll
        for (int fi = 0; fi < 5; ++fi)
#pragma unroll
            for (int ji = 0; ji < 4; ++ji)
                acc[fi][ji] = __builtin_amdgcn_mfma_f32_16x16x32_bf16(a[fi], bb[ji], acc[fi][ji], 0, 0, 0);
    }
#pragma unroll
    for (int fi = 0; fi < 5; ++fi)
#pragma unroll
        for (int ji = 0; ji < 4; ++ji)
#pragma unroll
            for (int r = 0; r < 4; ++r) {
                int f = (wave * 5 + fi) * 16 + lg * 4 + r;   // 0..319
                int j = j0 + ji * 16 + lr;                   // 0..4095
                int ft = f >> 4, floc = f & 15;
                int kt = j >> 6, jloc = j & 63;
                size_t base = (size_t)((b * 20 + ft) * 64 + kt) * YTILE;
                int byte = floc * 128 + (((jloc >> 3) * 16) ^ ((floc & 7) << 4)) + (jloc & 7) * 2;
                *(__bf16*)(Ytt + base + byte) = (__bf16)acc[fi][ji][r];
            }
}

// ---------------- K4: out = d_i * (adj @ Yt) + bias ------------------------
// v3: 512 thr = 8 waves = 4m x 2n. BM=128, BN=160, BK=64. Wave tile 32x80:
// 20 MFMA per 14 ds_read (was 10 per 12) -> total LDS reads 3.1 GB -> 1.8 GB.
// Ring of 4 step-buffers (4 x 36 KB = 144 KB) enables SINGLE barrier/step:
// stage at step t writes slot (t+2)%4 whose readers (step t-2) finished
// lgkmcnt(0) before barrier(t-1), which all waves passed before stage(t).
// Counted vmcnt identical to R8: 5 gloads/wave/step (36 real chunks + 4
// benign duplicates), vmcnt(10) = tile t landed, t+1/t+2 in flight.
// by-siblings (delta bid = 128 == 0 mod 8) share A panels on one XCD.
__global__ __launch_bounds__(512) void k_gemm_pipe(const char* __restrict__ adjb,
                                                   const char* __restrict__ ytt,
                                                   const float* __restrict__ d,
                                                   const float* __restrict__ bias,
                                                   float* __restrict__ out) {
    __shared__ __align__(16) char smem[4 * STEP2];   // 144 KB -> 1 block/CU
    const int bid = blockIdx.x;               // 0..255
    const int bx  = bid & 31;                 // 32 m-blocks of 128 rows
    const int b   = (bid >> 5) & 3;           // batch
    const int by  = bid >> 7;                 // 0..1 (160-f panel)
    const int w = threadIdx.x >> 6, lane = threadIdx.x & 63;
    const int wm = w >> 1, wn = w & 1;        // 4m x 2n
    const int lr = lane & 15, lg = lane >> 4;

    // --- staging plan: 36 chunks (16 A + 20 B); wave issues cids w*5+g ------
    const char* gp[5];   // per-chunk global base (incl. lane*16)
    int st[5];           // per-K-step source stride
    int lo[5];           // LDS byte offset within a step buffer
#pragma unroll
    for (int g = 0; g < 5; ++g) {
        int cid = w * 5 + g; if (cid >= 36) cid -= 36;   // 4 dup dummies (w=7)
        if (cid < 16) {  // A: adjb tile (b*NMT + 2bx + (cid>>3)), byte (cid&7)*1K
            gp[g] = adjb + (size_t)((b * NMT + 2 * bx + (cid >> 3)) * NKT) * TILE_BYTES
                    + (cid & 7) * 1024 + lane * 16;
            st[g] = TILE_BYTES;
            lo[g] = cid * 1024;
        } else {         // B: Ytt tile ft = by*10 + cc/2, half cc&1
            int cc = cid - 16;   // 0..19
            gp[g] = ytt + (size_t)((b * 20 + by * 10 + (cc >> 1)) * 64) * YTILE
                    + (cc & 1) * 1024 + lane * 16;
            st[g] = YTILE;
            lo[g] = 16384 + cc * 1024;
        }
    }

    // --- swizzled LDS read addresses ---------------------------------------
    uint32_t sb = (uint32_t)(uintptr_t)(__attribute__((address_space(3))) char*)smem;
    const int sw = (lr & 7) << 4;
    const uint32_t col0 = (uint32_t)((lg * 16) ^ sw);
    const uint32_t col1 = (uint32_t)(((4 + lg) * 16) ^ sw);
    const uint32_t rA0 = sb + (wm * 32 + lr) * 128;        // mi=0 rows
    const uint32_t rA1 = sb + (wm * 32 + 16 + lr) * 128;   // mi=1 rows
    uint32_t rB[5];
#pragma unroll
    for (int nt = 0; nt < 5; ++nt)
        rB[nt] = sb + 16384 + (wn * 5 + nt) * 2048 + lr * 128;

    f32x4 acc[2][5] = {};

#define STAGE(OFF, KT_) { _Pragma("unroll") \
    for (int g = 0; g < 5; ++g) \
        gload_lds16(gp[g] + (size_t)(KT_) * st[g], smem + (OFF) + lo[g]); }

#define SUBSTEP(S, TT)                                                                  \
    {                                                                                   \
        int ks = (TT) + 2 > NKT - 1 ? NKT - 1 : (TT) + 2;                               \
        STAGE((((S) + 2) & 3) * STEP2, ks)                                              \
        SB();                                                                           \
        asm volatile("s_waitcnt vmcnt(10)");                                            \
        SB();                                                                           \
        __builtin_amdgcn_s_barrier();                                                   \
        const uint32_t o_ = (S) * STEP2;                                                \
        bf16x8 a00, a01, a10, a11;                                                      \
        bf16x8 b0k0, b0k1, b1k0, b1k1, b2k0, b2k1, b3k0, b3k1, b4k0, b4k1;              \
        asm volatile("ds_read_b128 %0, %1" : "=v"(a00)  : "v"(o_ + rA0 + col0));        \
        asm volatile("ds_read_b128 %0, %1" : "=v"(a01)  : "v"(o_ + rA0 + col1));        \
        asm volatile("ds_read_b128 %0, %1" : "=v"(a10)  : "v"(o_ + rA1 + col0));        \
        asm volatile("ds_read_b128 %0, %1" : "=v"(a11)  : "v"(o_ + rA1 + col1));        \
        asm volatile("ds_read_b128 %0, %1" : "=v"(b0k0) : "v"(o_ + rB[0] + col0));      \
        asm volatile("ds_read_b128 %0, %1" : "=v"(b0k1) : "v"(o_ + rB[0] + col1));      \
        asm volatile("ds_read_b128 %0, %1" : "=v"(b1k0) : "v"(o_ + rB[1] + col0));      \
        asm volatile("ds_read_b128 %0, %1" : "=v"(b1k1) : "v"(o_ + rB[1] + col1));      \
        asm volatile("ds_read_b128 %0, %1" : "=v"(b2k0) : "v"(o_ + rB[2] + col0));      \
        asm volatile("ds_read_b128 %0, %1" : "=v"(b2k1) : "v"(o_ + rB[2] + col1));      \
        asm volatile("ds_read_b128 %0, %1" : "=v"(b3k0) : "v"(o_ + rB[3] + col0));      \
        asm volatile("ds_read_b128 %0, %1" : "=v"(b3k1) : "v"(o_ + rB[3] + col1));      \
        asm volatile("ds_read_b128 %0, %1" : "=v"(b4k0) : "v"(o_ + rB[4] + col0));      \
        asm volatile("ds_read_b128 %0, %1" : "=v"(b4k1) : "v"(o_ + rB[4] + col1));      \
        asm volatile("s_waitcnt lgkmcnt(0)");                                           \
        SB();                                                                           \
        __builtin_amdgcn_s_setprio(1);                                                  \
        acc[0][0] = __builtin_amdgcn_mfma_f32_16x16x32_bf16(a00, b0k0, acc[0][0], 0, 0, 0); \
        acc[0][1] = __builtin_amdgcn_mfma_f32_16x16x32_bf16(a00, b1k0, acc[0][1], 0, 0, 0); \
        acc[0][2] = __builtin_amdgcn_mfma_f32_16x16x32_bf16(a00, b2k0, acc[0][2], 0, 0, 0); \
        acc[0][3] = __builtin_amdgcn_mfma_f32_16x16x32_bf16(a00, b3k0, acc[0][3], 0, 0, 0); \
        acc[0][4] = __builtin_amdgcn_mfma_f32_16x16x32_bf16(a00, b4k0, acc[0][4], 0, 0, 0); \
        acc[1][0] = __builtin_amdgcn_mfma_f32_16x16x32_bf16(a10, b0k0, acc[1][0], 0, 0, 0); \
        acc[1][1] = __builtin_amdgcn_mfma_f32_16x16x32_bf16(a10, b1k0, acc[1][1], 0, 0, 0); \
        acc[1][2] = __builtin_amdgcn_mfma_f32_16x16x32_bf16(a10, b2k0, acc[1][2], 0, 0, 0); \
        acc[1][3] = __builtin_amdgcn_mfma_f32_16x16x32_bf16(a10, b3k0, acc[1][3], 0, 0, 0); \
        acc[1][4] = __builtin_amdgcn_mfma_f32_16x16x32_bf16(a10, b4k0, acc[1][4], 0, 0, 0); \
        acc[0][0] = __builtin_amdgcn_mfma_f32_16x16x32_bf16(a01, b0k1, acc[0][0], 0, 0, 0); \
        acc[0][1] = __builtin_amdgcn_mfma_f32_16x16x32_bf16(a01, b1k1, acc[0][1], 0, 0, 0); \
        acc[0][2] = __builtin_amdgcn_mfma_f32_16x16x32_bf16(a01, b2k1, acc[0][2], 0, 0, 0); \
        acc[0][3] = __builtin_amdgcn_mfma_f32_16x16x32_bf16(a01, b3k1, acc[0][3], 0, 0, 0); \
        acc[0][4] = __builtin_amdgcn_mfma_f32_16x16x32_bf16(a01, b4k1, acc[0][4], 0, 0, 0); \
        acc[1][0] = __builtin_amdgcn_mfma_f32_16x16x32_bf16(a11, b0k1, acc[1][0], 0, 0, 0); \
        acc[1][1] = __builtin_amdgcn_mfma_f32_16x16x32_bf16(a11, b1k1, acc[1][1], 0, 0, 0); \
        acc[1][2] = __builtin_amdgcn_mfma_f32_16x16x32_bf16(a11, b2k1, acc[1][2], 0, 0, 0); \
        acc[1][3] = __builtin_amdgcn_mfma_f32_16x16x32_bf16(a11, b3k1, acc[1][3], 0, 0, 0); \
        acc[1][4] = __builtin_amdgcn_mfma_f32_16x16x32_bf16(a11, b4k1, acc[1][4], 0, 0, 0); \
        __builtin_amdgcn_s_setprio(0);                                                  \
        SB();                                                                           \
    }

    // prologue: tiles 0,1 into slots 0,1 -> 10 outstanding per wave
    STAGE(0, 0)
    STAGE(STEP2, 1)
    for (int tt = 0; tt < NKT; tt += 4) {
        SUBSTEP(0, tt)
        SUBSTEP(1, tt + 1)
        SUBSTEP(2, tt + 2)
        SUBSTEP(3, tt + 3)
    }

    // epilogue: scale by d_i, add bias, store (f < 300 only)
    const int rowb = bx * 128 + wm * 32;
    float di[2][4];
#pragma unroll
    for (int mi = 0; mi < 2; ++mi)
#pragma unroll
        for (int r = 0; r < 4; ++r)
            di[mi][r] = d[b * N_ + rowb + mi * 16 + lg * 4 + r];
#pragma unroll
    for (int nt = 0; nt < 5; ++nt) {
        int f = by * 160 + wn * 80 + nt * 16 + lr;
        if (f < FOUT) {
            float bv = bias[f];
#pragma unroll
            for (int mi = 0; mi < 2; ++mi)
#pragma unroll
                for (int r = 0; r < 4; ++r) {
                    int i = rowb + mi * 16 + lg * 4 + r;
                    out[((size_t)b * N_ + i) * FOUT + f] = di[mi][r] * acc[mi][nt][r] + bv;
                }
        }
    }
#undef STAGE
#undef SUBSTEP
}

// ---------------- Fallback GEMM (fp32 adj direct; only if ws too small) ----
#define FB_LOAD(AV, BV, K0)                                                           \
    {                                                                                 \
        _Pragma("unroll")                                                             \
        for (int mi = 0; mi < 2; ++mi) {                                              \
            const float4* p = (const float4*)(adjf + (size_t)(rowbase + mi * 16 + lr) * N_ + (K0) + lg * 8); \
            float4 v0 = p[0], v1 = p[1];                                              \
            AV[mi][0] = (__bf16)v0.x; AV[mi][1] = (__bf16)v0.y;                       \
            AV[mi][2] = (__bf16)v0.z; AV[mi][3] = (__bf16)v0.w;                       \
            AV[mi][4] = (__bf16)v1.x; AV[mi][5] = (__bf16)v1.y;                       \
            AV[mi][6] = (__bf16)v1.z; AV[mi][7] = (__bf16)v1.w;                       \
        }                                                                             \
        _Pragma("unroll")                                                             \
        for (int nt = 0; nt < 10; ++nt) {                                             \
            int f = wn * 160 + nt * 16 + lr;                                          \
            BV[nt] = *(const bf16x8*)(Yb + (size_t)f * N_ + (K0) + lg * 8);           \
        }                                                                             \
    }
#define FB_MFMA(AV, BV)                                                               \
    {                                                                                 \
        _Pragma("unroll")                                                             \
        for (int mi = 0; mi < 2; ++mi)                                                \
            _Pragma("unroll")                                                         \
            for (int nt = 0; nt < 10; ++nt)                                           \
                acc[mi][nt] = __builtin_amdgcn_mfma_f32_16x16x32_bf16(AV[mi], BV[nt], acc[mi][nt], 0, 0, 0); \
    }

__global__ __launch_bounds__(256) void k_gemm_fb(const float* __restrict__ adj,
                                                 const __bf16* __restrict__ Yt,
                                                 const float* __restrict__ d,
                                                 const float* __restrict__ bias,
                                                 float* __restrict__ out) {
    int b    = blockIdx.y;
    int wave = threadIdx.x >> 6, lane = threadIdx.x & 63;
    int wm = wave & 1, wn = wave >> 1;
    int lr = lane & 15, lg = lane >> 4;
    int rowbase = blockIdx.x * 64 + wm * 32;
    const float*  adjf = adj + (size_t)b * N_ * N_;
    const __bf16* Yb   = Yt + (size_t)b * FP * N_;

    f32x4 acc[2][10] = {};
    bf16x8 aA[2], bA[10], aB[2], bB[10];

    FB_LOAD(aA, bA, 0)
    for (int k0 = 0; k0 < N_ - 64; k0 += 64) {
        FB_LOAD(aB, bB, k0 + 32)
        FB_MFMA(aA, bA)
        FB_LOAD(aA, bA, k0 + 64)
        FB_MFMA(aB, bB)
    }
    FB_LOAD(aB, bB, N_ - 32)
    FB_MFMA(aA, bA)
    FB_MFMA(aB, bB)

#pragma unroll
    for (int mi = 0; mi < 2; ++mi) {
        float di[4];
#pragma unroll
        for (int r = 0; r < 4; ++r)
            di[r] = d[b * N_ + rowbase + mi * 16 + lg * 4 + r];
#pragma unroll
        for (int nt = 0; nt < 10; ++nt) {
            int f = wn * 160 + nt * 16 + lr;
            if (f < FOUT) {
                float bv = bias[f];
#pragma unroll
                for (int r = 0; r < 4; ++r) {
                    int i = rowbase + mi * 16 + lg * 4 + r;
                    out[((size_t)b * N_ + i) * FOUT + f] = di[r] * acc[mi][nt][r] + bv;
                }
            }
        }
    }
}

extern "C" void kernel_launch(void* const* d_in, const int* in_sizes, int n_in,
                              void* d_out, int out_size, void* d_ws, size_t ws_size,
                              hipStream_t stream) {
    const float* text = (const float*)d_in[0];
    const float* adj  = (const float*)d_in[1];
    const float* W    = (const float*)d_in[2];
    const float* bias = (const float*)d_in[3];
    float* out = (float*)d_out;

    char* ws = (char*)d_ws;
    __bf16* Wt   = (__bf16*)(ws + WT_OFF);
    float*  dv   = (float*)(ws + D_OFF);
    __bf16* Tsc  = (__bf16*)(ws + TSC_OFF);
    char*   Ybuf = ws + YT_OFF;
    char*   adjb = ws + ADJB_OFF;

    bool big = ws_size >= (size_t)ADJB_OFF + ADJB_BYTES;

    k_wt<<<dim3((FP * FP + 255) / 256), dim3(256), 0, stream>>>(W, Wt);
    if (big)
        k_rowsum_cvt<<<dim3(B_ * N_ / 4), dim3(256), 0, stream>>>(adj, dv, adjb);
    else
        k_rowsum<<<dim3(B_ * N_ / 4), dim3(256), 0, stream>>>(adj, dv);
    k_tsc<<<dim3(B_ * N_ * FP / 256), dim3(256), 0, stream>>>(text, dv, Tsc);
    if (big) {
        k_y_t<<<dim3(N_ / 64, B_), dim3(256), 0, stream>>>(Wt, Tsc, Ybuf);
        k_gemm_pipe<<<dim3(256), dim3(512), 0, stream>>>(adjb, Ybuf, dv, bias, out);
    } else {
        k_y<<<dim3(N_ / 64, B_), dim3(256), 0, stream>>>(Wt, Tsc, (__bf16*)Ybuf);
        k_gemm_fb<<<dim3(N_ / 64, B_), dim3(256), 0, stream>>>(adj, (__bf16*)Ybuf, dv, bias, out);
    }
}

// Round 10
// 203.594 us; speedup vs baseline: 1.1556x; 1.1556x over previous
//
#include <hip/hip_runtime.h>
#include <hip/hip_bf16.h>

typedef __bf16 bf16x8 __attribute__((ext_vector_type(8)));
typedef __bf16 bf16x4 __attribute__((ext_vector_type(4)));
typedef float  f32x4  __attribute__((ext_vector_type(4)));

#define B_   4
#define N_   4096
#define FIN  300
#define FOUT 300
#define FP   320   // padded feature dim (multiple of 32)
#define MT   64    // adjb tile rows
#define KT   64    // adjb tile cols
#define NMT  (N_/MT)
#define NKT  (N_/KT)
#define TILE_BYTES (MT*KT*2)   // 8192
#define STEP_BYTES 18432       // per-K-step LDS: A 8 KB + B 10 KB
#define YTILE 2048             // Ytt tile: 16 f x 64 k bf16

// ws layout (bytes)
#define WT_OFF   0                    // Wt   bf16 [FP][FP]
#define D_OFF    (512*1024)           // d    fp32 [B_*N_]
#define TSC_OFF  (1024*1024)          // Tsc  bf16 [B_*N_][FP]
#define YT_OFF   (16*1024*1024)       // Yt / Ytt (tiled)  ~10.5 MB
#define ADJB_OFF (32*1024*1024)       // adjb bf16 tiled+swizzled [B_][NMT][NKT][8KB]
#define ADJB_BYTES ((size_t)B_ * N_ * N_ * 2)

#define SB() __builtin_amdgcn_sched_barrier(0)

__device__ __forceinline__ void gload_lds16(const void* g, void* l) {
    __builtin_amdgcn_global_load_lds((const __attribute__((address_space(1))) void*)g,
                                     (__attribute__((address_space(3))) void*)l, 16, 0, 0);
}

// ---------------- K0: Wt[f][k] = bf16(W[k][f]), zero-padded ----------------
__global__ void k_wt(const float* __restrict__ W, __bf16* __restrict__ Wt) {
    int t = blockIdx.x * 256 + threadIdx.x;
    if (t >= FP * FP) return;
    int f = t / FP, k = t - f * FP;
    float v = (f < FOUT && k < FIN) ? W[k * FOUT + f] : 0.0f;
    Wt[t] = (__bf16)v;
}

// ---------------- K1a: rowsum only (fallback path) -------------------------
__global__ void k_rowsum(const float* __restrict__ adj, float* __restrict__ d) {
    int row  = blockIdx.x * 4 + (threadIdx.x >> 6);
    int lane = threadIdx.x & 63;
    const float4* p = (const float4*)(adj + (size_t)row * N_);
    float s = 0.0f;
#pragma unroll
    for (int it = 0; it < 16; ++it) {
        float4 v = p[it * 64 + lane];
        s += v.x + v.y + v.z + v.w;
    }
#pragma unroll
    for (int off = 32; off; off >>= 1) s += __shfl_xor(s, off);
    if (lane == 0) d[row] = rsqrtf(s + 1.0f);
}

// ---------------- K1b v2: rowsum + tiled/swizzled bf16 copy, COALESCED -----
// Global tile layout (unchanged): adjb[(b*NMT+mt)*NKT + kt] is 8 KB = rows
// [mloc][64 bf16]; 16-B chunk c of a row at byte mloc*128 + (c*16 ^
// ((mloc&7)<<4)); chunk c holds cols 8c..8c+7.
// v2: block = one 64-row panel (mt,b); 8 waves, wave w owns rows w*8..+8.
// Per 256-col group: coalesced 1 KB float4 row-reads -> bf16 -> ds_write
// into a 32 KB LDS image of 4 tiles in EXACT global layout -> barrier ->
// linear LDS->global copy (512 thr x 16 B x 4: fully coalesced line writes).
__global__ __launch_bounds__(512) void k_rowsum_cvt(const float* __restrict__ adj,
                                                    float* __restrict__ d,
                                                    char* __restrict__ adjb) {
    __shared__ __align__(16) char lds[4 * TILE_BYTES];   // 32 KB
    const int mt = blockIdx.x, b = blockIdx.y;
    const int t = threadIdx.x, w = t >> 6, lane = t & 63;
    const int tloc = lane >> 4;                 // which of the 4 tiles in group
    const int chunk = (lane & 15) >> 1;         // 16-B chunk within row
    const int sub8  = (lane & 1) * 8;           // byte offset within chunk
    const size_t rowbase = (size_t)b * N_ + mt * 64;
    char* gbase = adjb + (size_t)((b * NMT + mt) * NKT) * TILE_BYTES;

    float psum[8] = {};
    for (int g = 0; g < 16; ++g) {
        // phase 1: read 8 rows x 256 cols, convert, ds_write in tile layout
#pragma unroll
        for (int rr = 0; rr < 8; ++rr) {
            int r = w * 8 + rr;
            float4 v = *(const float4*)(adj + (rowbase + r) * N_ + g * 256 + lane * 4);
            psum[rr] += v.x + v.y + v.z + v.w;
            bf16x4 o;
            o[0] = (__bf16)v.x; o[1] = (__bf16)v.y; o[2] = (__bf16)v.z; o[3] = (__bf16)v.w;
            int byte = tloc * TILE_BYTES + r * 128 + ((chunk * 16) ^ ((r & 7) << 4)) + sub8;
            *(bf16x4*)(lds + byte) = o;
        }
        __syncthreads();
        // phase 2: linear copy-out of 4 complete tiles (kt = 4g .. 4g+3)
#pragma unroll
        for (int i = 0; i < 4; ++i) {
            int idx = i * 512 + t;              // 16-B unit 0..2047
            int tl = idx >> 9, off = (idx & 511) * 16;
            *(f32x4*)(gbase + (size_t)(g * 4 + tl) * TILE_BYTES + off) =
                *(const f32x4*)(lds + tl * TILE_BYTES + off);
        }
        __syncthreads();
    }
    // rowsum reduce: lane covered disjoint cols {g*256 + lane*4 ..+3}
#pragma unroll
    for (int rr = 0; rr < 8; ++rr) {
        float s = psum[rr];
#pragma unroll
        for (int off = 32; off; off >>= 1) s += __shfl_xor(s, off);
        if (lane == 0) d[rowbase + w * 8 + rr] = rsqrtf(s + 1.0f);
    }
}

// ---------------- K2: Tsc[j][k] = bf16(d[j]*text[j][k]), K zero-padded -----
__global__ void k_tsc(const float* __restrict__ text, const float* __restrict__ d,
                      __bf16* __restrict__ Tsc) {
    int t = blockIdx.x * 256 + threadIdx.x;
    int j = t / FP;
    int k = t - j * FP;
    float v = 0.0f;
    if (k < FIN) v = d[j] * text[(size_t)j * FIN + k];
    Tsc[t] = (__bf16)v;
}

// ---------------- K3a: plain Yt (fallback): Yt[b][f][j] --------------------
__global__ __launch_bounds__(256) void k_y(const __bf16* __restrict__ Wt,
                                           const __bf16* __restrict__ Tsc,
                                           __bf16* __restrict__ Yt) {
    int b    = blockIdx.y;
    int j0   = blockIdx.x * 64;
    int wave = threadIdx.x >> 6, lane = threadIdx.x & 63;
    int lr = lane & 15, lg = lane >> 4;
    f32x4 acc[5][4] = {};
    for (int k0 = 0; k0 < FP; k0 += 32) {
        bf16x8 a[5], bb[4];
#pragma unroll
        for (int fi = 0; fi < 5; ++fi) {
            int f = (wave * 5 + fi) * 16 + lr;
            a[fi] = *(const bf16x8*)(Wt + (size_t)f * FP + k0 + lg * 8);
        }
#pragma unroll
        for (int ji = 0; ji < 4; ++ji) {
            int j = j0 + ji * 16 + lr;
            bb[ji] = *(const bf16x8*)(Tsc + ((size_t)(b * N_ + j)) * FP + k0 + lg * 8);
        }
#pragma unroll
        for (int fi = 0; fi < 5; ++fi)
#pragma unroll
            for (int ji = 0; ji < 4; ++ji)
                acc[fi][ji] = __builtin_amdgcn_mfma_f32_16x16x32_bf16(a[fi], bb[ji], acc[fi][ji], 0, 0, 0);
    }
#pragma unroll
    for (int fi = 0; fi < 5; ++fi)
#pragma unroll
        for (int ji = 0; ji < 4; ++ji)
#pragma unroll
            for (int r = 0; r < 4; ++r) {
                int f = (wave * 5 + fi) * 16 + lg * 4 + r;
                int j = j0 + ji * 16 + lr;
                Yt[((size_t)b * FP + f) * N_ + j] = (__bf16)acc[fi][ji][r];
            }
}

// ---------------- K3b: tiled+swizzled Ytt for the pipelined GEMM -----------
// Ytt tile (ft, kt): 2 KB = 16 f-rows x 64 k bf16, tile idx (b*20+ft)*64+kt.
// Within tile: row floc (=f&15) at byte floc*128; 16-B chunk c of the row at
// byte (c*16 ^ ((floc&7)<<4)); elements (k&7) consecutive inside the chunk.
__global__ __launch_bounds__(256) void k_y_t(const __bf16* __restrict__ Wt,
                                             const __bf16* __restrict__ Tsc,
                                             char* __restrict__ Ytt) {
    int b    = blockIdx.y;
    int j0   = blockIdx.x * 64;
    int wave = threadIdx.x >> 6, lane = threadIdx.x & 63;
    int lr = lane & 15, lg = lane >> 4;
    f32x4 acc[5][4] = {};
    for (int k0 = 0; k0 < FP; k0 += 32) {
        bf16x8 a[5], bb[4];
#pragma unroll
        for (int fi = 0; fi < 5; ++fi) {
            int f = (wave * 5 + fi) * 16 + lr;
            a[fi] = *(const bf16x8*)(Wt + (size_t)f * FP + k0 + lg * 8);
        }
#pragma unroll
        for (int ji = 0; ji < 4; ++ji) {
            int j = j0 + ji * 16 + lr;
            bb[ji] = *(const bf16x8*)(Tsc + ((size_t)(b * N_ + j)) * FP + k0 + lg * 8);
        }
#pragma unroll
        for (int fi = 0; fi < 5; ++fi)
#pragma unroll
            for (int ji = 0; ji < 4; ++ji)
                acc[fi][ji] = __builtin_amdgcn_mfma_f32_16x16x32_bf16(a[fi], bb[ji], acc[fi][ji], 0, 0, 0);
    }
#pragma unroll
    for (int fi = 0; fi < 5; ++fi)
#pragma unroll
        for (int ji = 0; ji < 4; ++ji)
#pragma unroll
            for (int r = 0; r < 4; ++r) {
                int f = (wave * 5 + fi) * 16 + lg * 4 + r;   // 0..319
                int j = j0 + ji * 16 + lr;                   // 0..4095
                int ft = f >> 4, floc = f & 15;
                int kt = j >> 6, jloc = j & 63;
                size_t base = (size_t)((b * 20 + ft) * 64 + kt) * YTILE;
                int byte = floc * 128 + (((jloc >> 3) * 16) ^ ((floc & 7) << 4)) + (jloc & 7) * 2;
                *(__bf16*)(Ytt + base + byte) = (__bf16)acc[fi][ji][r];
            }
}

// ---------------- K4: out = d_i * (adj @ Yt) + bias ------------------------
// R8 structure (verbatim): BOTH operands staged via global_load_lds into a
// ring of 3 LDS buffers (3 x 18 KB), stage distance 2, counted vmcnt.
// 256 thr = 4 waves; wave w owns rows bx*64 + w*16, all waves share the 80-f
// B panel. Per step each wave issues EXACTLY 5 gload_lds (20 total: 8 A + 10
// B + 2 idempotent dummies) -> uniform vmcnt(10). Raw s_barrier (no drain).
__global__ __launch_bounds__(256) void k_gemm_pipe(const char* __restrict__ adjb,
                                                   const char* __restrict__ ytt,
                                                   const float* __restrict__ d,
                                                   const float* __restrict__ bias,
                                                   float* __restrict__ out) {
    __shared__ __align__(16) char smem[3 * STEP_BYTES];   // 54 KB -> 2 blocks/CU
    const int bid = blockIdx.x;
    const int bx = bid & 63, by = (bid >> 6) & 3, b = bid >> 8;
    const int w = threadIdx.x >> 6, lane = threadIdx.x & 63;
    const int lr = lane & 15, lg = lane >> 4;

    // --- staging plan: chunk cid = (w*5+g) mod 18; cid<8 -> A, else B ------
    const char* gp[5];   // per-chunk global base (incl. lane*16)
    int st[5];           // per-K-step stride of that chunk's source
    int lo[5];           // LDS byte offset within a step buffer
#pragma unroll
    for (int g = 0; g < 5; ++g) {
        int cid = w * 5 + g; if (cid >= 18) cid -= 18;
        if (cid < 8) {   // A: adjb tile (b*NMT+bx, kt), byte cid*1024
            gp[g] = adjb + (size_t)((b * NMT + bx) * NKT) * TILE_BYTES + cid * 1024 + lane * 16;
            st[g] = TILE_BYTES;
            lo[g] = cid * 1024;
        } else {         // B: Ytt tile (b*20 + by*5 + cc/2, kt), half cc&1
            int cc = cid - 8;
            gp[g] = ytt + (size_t)((b * 20 + by * 5 + (cc >> 1)) * 64) * YTILE + (cc & 1) * 1024 + lane * 16;
            st[g] = YTILE;
            lo[g] = 8192 + cc * 1024;
        }
    }

    // --- swizzled LDS read addresses ---------------------------------------
    uint32_t sb = (uint32_t)(uintptr_t)(__attribute__((address_space(3))) char*)smem;
    const int sw = (lr & 7) << 4;
    const uint32_t col0 = (uint32_t)((lg * 16) ^ sw);          // kh=0
    const uint32_t col1 = (uint32_t)(((4 + lg) * 16) ^ sw);    // kh=1
    const uint32_t rowA = sb + (w * 16 + lr) * 128;            // A rows w*16..+16
    uint32_t rowB[5];
#pragma unroll
    for (int nt = 0; nt < 5; ++nt) rowB[nt] = sb + 8192 + nt * YTILE + lr * 128;

    f32x4 acc[5] = {};
    uint32_t oc = 0, on = STEP_BYTES, ot = 2 * STEP_BYTES;

#define STAGE(OFF, KT_) { _Pragma("unroll") \
    for (int g = 0; g < 5; ++g) \
        gload_lds16(gp[g] + (size_t)(KT_) * st[g], smem + (OFF) + lo[g]); }

    // prologue: tiles 0,1 -> 10 outstanding per wave
    STAGE(oc, 0)
    STAGE(on, 1)
    for (int t = 0; t < NKT; ++t) {
        int ks = t + 2 > NKT - 1 ? NKT - 1 : t + 2;
        SB();
        STAGE(ot, ks)                         // +5 -> <=15 outstanding
        SB();
        asm volatile("s_waitcnt vmcnt(10)");  // tile t complete; t+1,t+2 in flight
        SB();
        __builtin_amdgcn_s_barrier();         // all waves' tile-t chunks landed
        bf16x8 a0, a1, b00, b01, b10, b11, b20, b21, b30, b31, b40, b41;
        asm volatile("ds_read_b128 %0, %1" : "=v"(a0)  : "v"(oc + rowA + col0));
        asm volatile("ds_read_b128 %0, %1" : "=v"(a1)  : "v"(oc + rowA + col1));
        asm volatile("ds_read_b128 %0, %1" : "=v"(b00) : "v"(oc + rowB[0] + col0));
        asm volatile("ds_read_b128 %0, %1" : "=v"(b01) : "v"(oc + rowB[0] + col1));
        asm volatile("ds_read_b128 %0, %1" : "=v"(b10) : "v"(oc + rowB[1] + col0));
        asm volatile("ds_read_b128 %0, %1" : "=v"(b11) : "v"(oc + rowB[1] + col1));
        asm volatile("ds_read_b128 %0, %1" : "=v"(b20) : "v"(oc + rowB[2] + col0));
        asm volatile("ds_read_b128 %0, %1" : "=v"(b21) : "v"(oc + rowB[2] + col1));
        asm volatile("ds_read_b128 %0, %1" : "=v"(b30) : "v"(oc + rowB[3] + col0));
        asm volatile("ds_read_b128 %0, %1" : "=v"(b31) : "v"(oc + rowB[3] + col1));
        asm volatile("ds_read_b128 %0, %1" : "=v"(b40) : "v"(oc + rowB[4] + col0));
        asm volatile("ds_read_b128 %0, %1" : "=v"(b41) : "v"(oc + rowB[4] + col1));
        asm volatile("s_waitcnt lgkmcnt(0)");
        SB();                                  // rule 18: fence MFMA below the wait
        __builtin_amdgcn_s_barrier();          // all waves done reading -> buf reusable
        acc[0] = __builtin_amdgcn_mfma_f32_16x16x32_bf16(a0, b00, acc[0], 0, 0, 0);
        acc[0] = __builtin_amdgcn_mfma_f32_16x16x32_bf16(a1, b01, acc[0], 0, 0, 0);
        acc[1] = __builtin_amdgcn_mfma_f32_16x16x32_bf16(a0, b10, acc[1], 0, 0, 0);
        acc[1] = __builtin_amdgcn_mfma_f32_16x16x32_bf16(a1, b11, acc[1], 0, 0, 0);
        acc[2] = __builtin_amdgcn_mfma_f32_16x16x32_bf16(a0, b20, acc[2], 0, 0, 0);
        acc[2] = __builtin_amdgcn_mfma_f32_16x16x32_bf16(a1, b21, acc[2], 0, 0, 0);
        acc[3] = __builtin_amdgcn_mfma_f32_16x16x32_bf16(a0, b30, acc[3], 0, 0, 0);
        acc[3] = __builtin_amdgcn_mfma_f32_16x16x32_bf16(a1, b31, acc[3], 0, 0, 0);
        acc[4] = __builtin_amdgcn_mfma_f32_16x16x32_bf16(a0, b40, acc[4], 0, 0, 0);
        acc[4] = __builtin_amdgcn_mfma_f32_16x16x32_bf16(a1, b41, acc[4], 0, 0, 0);
        SB();
        uint32_t tmp = oc; oc = on; on = ot; ot = tmp;   // rotate ring
    }

    // epilogue: scale by d_i, add bias, store (f < 300 only)
    const int rowb = bx * 64 + w * 16;
    float di[4];
#pragma unroll
    for (int r = 0; r < 4; ++r)
        di[r] = d[b * N_ + rowb + lg * 4 + r];
#pragma unroll
    for (int nt = 0; nt < 5; ++nt) {
        int f = by * 80 + nt * 16 + lr;
        if (f < FOUT) {
            float bv = bias[f];
#pragma unroll
            for (int r = 0; r < 4; ++r) {
                int i = rowb + lg * 4 + r;
                out[((size_t)b * N_ + i) * FOUT + f] = di[r] * acc[nt][r] + bv;
            }
        }
    }
#undef STAGE
}

// ---------------- Fallback GEMM (fp32 adj direct; only if ws too small) ----
#define FB_LOAD(AV, BV, K0)                                                           \
    {                                                                                 \
        _Pragma("unroll")                                                             \
        for (int mi = 0; mi < 2; ++mi) {                                              \
            const float4* p = (const float4*)(adjf + (size_t)(rowbase + mi * 16 + lr) * N_ + (K0) + lg * 8); \
            float4 v0 = p[0], v1 = p[1];                                              \
            AV[mi][0] = (__bf16)v0.x; AV[mi][1] = (__bf16)v0.y;                       \
            AV[mi][2] = (__bf16)v0.z; AV[mi][3] = (__bf16)v0.w;                       \
            AV[mi][4] = (__bf16)v1.x; AV[mi][5] = (__bf16)v1.y;                       \
            AV[mi][6] = (__bf16)v1.z; AV[mi][7] = (__bf16)v1.w;                       \
        }                                                                             \
        _Pragma("unroll")                                                             \
        for (int nt = 0; nt < 10; ++nt) {                                             \
            int f = wn * 160 + nt * 16 + lr;                                          \
            BV[nt] = *(const bf16x8*)(Yb + (size_t)f * N_ + (K0) + lg * 8);           \
        }                                                                             \
    }
#define FB_MFMA(AV, BV)                                                               \
    {                                                                                 \
        _Pragma("unroll")                                                             \
        for (int mi = 0; mi < 2; ++mi)                                                \
            _Pragma("unroll")                                                         \
            for (int nt = 0; nt < 10; ++nt)                                           \
                acc[mi][nt] = __builtin_amdgcn_mfma_f32_16x16x32_bf16(AV[mi], BV[nt], acc[mi][nt], 0, 0, 0); \
    }

__global__ __launch_bounds__(256) void k_gemm_fb(const float* __restrict__ adj,
                                                 const __bf16* __restrict__ Yt,
                                                 const float* __restrict__ d,
                                                 const float* __restrict__ bias,
                                                 float* __restrict__ out) {
    int b    = blockIdx.y;
    int wave = threadIdx.x >> 6, lane = threadIdx.x & 63;
    int wm = wave & 1, wn = wave >> 1;
    int lr = lane & 15, lg = lane >> 4;
    int rowbase = blockIdx.x * 64 + wm * 32;
    const float*  adjf = adj + (size_t)b * N_ * N_;
    const __bf16* Yb   = Yt + (size_t)b * FP * N_;

    f32x4 acc[2][10] = {};
    bf16x8 aA[2], bA[10], aB[2], bB[10];

    FB_LOAD(aA, bA, 0)
    for (int k0 = 0; k0 < N_ - 64; k0 += 64) {
        FB_LOAD(aB, bB, k0 + 32)
        FB_MFMA(aA, bA)
        FB_LOAD(aA, bA, k0 + 64)
        FB_MFMA(aB, bB)
    }
    FB_LOAD(aB, bB, N_ - 32)
    FB_MFMA(aA, bA)
    FB_MFMA(aB, bB)

#pragma unroll
    for (int mi = 0; mi < 2; ++mi) {
        float di[4];
#pragma unroll
        for (int r = 0; r < 4; ++r)
            di[r] = d[b * N_ + rowbase + mi * 16 + lg * 4 + r];
#pragma unroll
        for (int nt = 0; nt < 10; ++nt) {
            int f = wn * 160 + nt * 16 + lr;
            if (f < FOUT) {
                float bv = bias[f];
#pragma unroll
                for (int r = 0; r < 4; ++r) {
                    int i = rowbase + mi * 16 + lg * 4 + r;
                    out[((size_t)b * N_ + i) * FOUT + f] = di[r] * acc[mi][nt][r] + bv;
                }
            }
        }
    }
}

extern "C" void kernel_launch(void* const* d_in, const int* in_sizes, int n_in,
                              void* d_out, int out_size, void* d_ws, size_t ws_size,
                              hipStream_t stream) {
    const float* text = (const float*)d_in[0];
    const float* adj  = (const float*)d_in[1];
    const float* W    = (const float*)d_in[2];
    const float* bias = (const float*)d_in[3];
    float* out = (float*)d_out;

    char* ws = (char*)d_ws;
    __bf16* Wt   = (__bf16*)(ws + WT_OFF);
    float*  dv   = (float*)(ws + D_OFF);
    __bf16* Tsc  = (__bf16*)(ws + TSC_OFF);
    char*   Ybuf = ws + YT_OFF;
    char*   adjb = ws + ADJB_OFF;

    bool big = ws_size >= (size_t)ADJB_OFF + ADJB_BYTES;

    k_wt<<<dim3((FP * FP + 255) / 256), dim3(256), 0, stream>>>(W, Wt);
    if (big)
        k_rowsum_cvt<<<dim3(NMT, B_), dim3(512), 0, stream>>>(adj, dv, adjb);
    else
        k_rowsum<<<dim3(B_ * N_ / 4), dim3(256), 0, stream>>>(adj, dv);
    k_tsc<<<dim3(B_ * N_ * FP / 256), dim3(256), 0, stream>>>(text, dv, Tsc);
    if (big) {
        k_y_t<<<dim3(N_ / 64, B_), dim3(256), 0, stream>>>(Wt, Tsc, Ybuf);
        k_gemm_pipe<<<dim3(1024), dim3(256), 0, stream>>>(adjb, Ybuf, dv, bias, out);
    } else {
        k_y<<<dim3(N_ / 64, B_), dim3(256), 0, stream>>>(Wt, Tsc, (__bf16*)Ybuf);
        k_gemm_fb<<<dim3(N_ / 64, B_), dim3(256), 0, stream>>>(adj, (__bf16*)Ybuf, dv, bias, out);
    }
}

// Round 11
// 193.680 us; speedup vs baseline: 1.2148x; 1.0512x over previous
//
#include <hip/hip_runtime.h>
#include <hip/hip_bf16.h>

typedef __bf16 bf16x8 __attribute__((ext_vector_type(8)));
typedef __bf16 bf16x4 __attribute__((ext_vector_type(4)));
typedef float  f32x4  __attribute__((ext_vector_type(4)));

#define B_   4
#define N_   4096
#define FIN  300
#define FOUT 300
#define FP   320   // padded feature dim (multiple of 32)
#define MT   64    // adjb tile rows
#define KT   64    // adjb tile cols
#define NMT  (N_/MT)
#define NKT  (N_/KT)
#define TILE_BYTES (MT*KT*2)   // 8192
#define YTILE 2048             // Ytt tile: 16 f x 64 k bf16
#define STEP_B2 26624          // per-K-step LDS: A 16 KB + B 10 KB

// ws layout (bytes)
#define WT_OFF   0                    // Wt   bf16 [FP][FP]
#define D_OFF    (512*1024)           // d    fp32 [B_*N_]
#define TSC_OFF  (1024*1024)          // Tsc  bf16 [B_*N_][FP]
#define YT_OFF   (16*1024*1024)       // Yt / Ytt (tiled)  ~10.5 MB
#define ADJB_OFF (32*1024*1024)       // adjb bf16 tiled+swizzled [B_][NMT][NKT][8KB]
#define ADJB_BYTES ((size_t)B_ * N_ * N_ * 2)

#define SB() __builtin_amdgcn_sched_barrier(0)

__device__ __forceinline__ void gload_lds16(const void* g, void* l) {
    __builtin_amdgcn_global_load_lds((const __attribute__((address_space(1))) void*)g,
                                     (__attribute__((address_space(3))) void*)l, 16, 0, 0);
}

// ---------------- K0: Wt[f][k] = bf16(W[k][f]), zero-padded ----------------
__global__ void k_wt(const float* __restrict__ W, __bf16* __restrict__ Wt) {
    int t = blockIdx.x * 256 + threadIdx.x;
    if (t >= FP * FP) return;
    int f = t / FP, k = t - f * FP;
    float v = (f < FOUT && k < FIN) ? W[k * FOUT + f] : 0.0f;
    Wt[t] = (__bf16)v;
}

// ---------------- K1a: rowsum only (fallback path) -------------------------
__global__ void k_rowsum(const float* __restrict__ adj, float* __restrict__ d) {
    int row  = blockIdx.x * 4 + (threadIdx.x >> 6);
    int lane = threadIdx.x & 63;
    const float4* p = (const float4*)(adj + (size_t)row * N_);
    float s = 0.0f;
#pragma unroll
    for (int it = 0; it < 16; ++it) {
        float4 v = p[it * 64 + lane];
        s += v.x + v.y + v.z + v.w;
    }
#pragma unroll
    for (int off = 32; off; off >>= 1) s += __shfl_xor(s, off);
    if (lane == 0) d[row] = rsqrtf(s + 1.0f);
}

// ---------------- K1b v2: rowsum + tiled/swizzled bf16 copy, COALESCED -----
// (R10-verified.) Global tile layout: adjb[(b*NMT+mt)*NKT + kt] is 8 KB =
// rows [mloc][64 bf16]; 16-B chunk c of a row at byte mloc*128 + (c*16 ^
// ((mloc&7)<<4)).
__global__ __launch_bounds__(512) void k_rowsum_cvt(const float* __restrict__ adj,
                                                    float* __restrict__ d,
                                                    char* __restrict__ adjb) {
    __shared__ __align__(16) char lds[4 * TILE_BYTES];   // 32 KB
    const int mt = blockIdx.x, b = blockIdx.y;
    const int t = threadIdx.x, w = t >> 6, lane = t & 63;
    const int tloc = lane >> 4;                 // which of the 4 tiles in group
    const int chunk = (lane & 15) >> 1;         // 16-B chunk within row
    const int sub8  = (lane & 1) * 8;           // byte offset within chunk
    const size_t rowbase = (size_t)b * N_ + mt * 64;
    char* gbase = adjb + (size_t)((b * NMT + mt) * NKT) * TILE_BYTES;

    float psum[8] = {};
    for (int g = 0; g < 16; ++g) {
#pragma unroll
        for (int rr = 0; rr < 8; ++rr) {
            int r = w * 8 + rr;
            float4 v = *(const float4*)(adj + (rowbase + r) * N_ + g * 256 + lane * 4);
            psum[rr] += v.x + v.y + v.z + v.w;
            bf16x4 o;
            o[0] = (__bf16)v.x; o[1] = (__bf16)v.y; o[2] = (__bf16)v.z; o[3] = (__bf16)v.w;
            int byte = tloc * TILE_BYTES + r * 128 + ((chunk * 16) ^ ((r & 7) << 4)) + sub8;
            *(bf16x4*)(lds + byte) = o;
        }
        __syncthreads();
#pragma unroll
        for (int i = 0; i < 4; ++i) {
            int idx = i * 512 + t;              // 16-B unit 0..2047
            int tl = idx >> 9, off = (idx & 511) * 16;
            *(f32x4*)(gbase + (size_t)(g * 4 + tl) * TILE_BYTES + off) =
                *(const f32x4*)(lds + tl * TILE_BYTES + off);
        }
        __syncthreads();
    }
#pragma unroll
    for (int rr = 0; rr < 8; ++rr) {
        float s = psum[rr];
#pragma unroll
        for (int off = 32; off; off >>= 1) s += __shfl_xor(s, off);
        if (lane == 0) d[rowbase + w * 8 + rr] = rsqrtf(s + 1.0f);
    }
}

// ---------------- K2: Tsc[j][k] = bf16(d[j]*text[j][k]), K zero-padded -----
__global__ void k_tsc(const float* __restrict__ text, const float* __restrict__ d,
                      __bf16* __restrict__ Tsc) {
    int t = blockIdx.x * 256 + threadIdx.x;
    int j = t / FP;
    int k = t - j * FP;
    float v = 0.0f;
    if (k < FIN) v = d[j] * text[(size_t)j * FIN + k];
    Tsc[t] = (__bf16)v;
}

// ---------------- K3a: plain Yt (fallback): Yt[b][f][j] --------------------
__global__ __launch_bounds__(256) void k_y(const __bf16* __restrict__ Wt,
                                           const __bf16* __restrict__ Tsc,
                                           __bf16* __restrict__ Yt) {
    int b    = blockIdx.y;
    int j0   = blockIdx.x * 64;
    int wave = threadIdx.x >> 6, lane = threadIdx.x & 63;
    int lr = lane & 15, lg = lane >> 4;
    f32x4 acc[5][4] = {};
    for (int k0 = 0; k0 < FP; k0 += 32) {
        bf16x8 a[5], bb[4];
#pragma unroll
        for (int fi = 0; fi < 5; ++fi) {
            int f = (wave * 5 + fi) * 16 + lr;
            a[fi] = *(const bf16x8*)(Wt + (size_t)f * FP + k0 + lg * 8);
        }
#pragma unroll
        for (int ji = 0; ji < 4; ++ji) {
            int j = j0 + ji * 16 + lr;
            bb[ji] = *(const bf16x8*)(Tsc + ((size_t)(b * N_ + j)) * FP + k0 + lg * 8);
        }
#pragma unroll
        for (int fi = 0; fi < 5; ++fi)
#pragma unroll
            for (int ji = 0; ji < 4; ++ji)
                acc[fi][ji] = __builtin_amdgcn_mfma_f32_16x16x32_bf16(a[fi], bb[ji], acc[fi][ji], 0, 0, 0);
    }
#pragma unroll
    for (int fi = 0; fi < 5; ++fi)
#pragma unroll
        for (int ji = 0; ji < 4; ++ji)
#pragma unroll
            for (int r = 0; r < 4; ++r) {
                int f = (wave * 5 + fi) * 16 + lg * 4 + r;
                int j = j0 + ji * 16 + lr;
                Yt[((size_t)b * FP + f) * N_ + j] = (__bf16)acc[fi][ji][r];
            }
}

// ---------------- K3b: tiled+swizzled Ytt for the pipelined GEMM -----------
// Ytt tile (ft, kt): 2 KB = 16 f-rows x 64 k bf16, tile idx (b*20+ft)*64+kt.
// Within tile: row floc at byte floc*128; 16-B chunk c at byte
// (c*16 ^ ((floc&7)<<4)); elements (k&7) consecutive inside the chunk.
__global__ __launch_bounds__(256) void k_y_t(const __bf16* __restrict__ Wt,
                                             const __bf16* __restrict__ Tsc,
                                             char* __restrict__ Ytt) {
    int b    = blockIdx.y;
    int j0   = blockIdx.x * 64;
    int wave = threadIdx.x >> 6, lane = threadIdx.x & 63;
    int lr = lane & 15, lg = lane >> 4;
    f32x4 acc[5][4] = {};
    for (int k0 = 0; k0 < FP; k0 += 32) {
        bf16x8 a[5], bb[4];
#pragma unroll
        for (int fi = 0; fi < 5; ++fi) {
            int f = (wave * 5 + fi) * 16 + lr;
            a[fi] = *(const bf16x8*)(Wt + (size_t)f * FP + k0 + lg * 8);
        }
#pragma unroll
        for (int ji = 0; ji < 4; ++ji) {
            int j = j0 + ji * 16 + lr;
            bb[ji] = *(const bf16x8*)(Tsc + ((size_t)(b * N_ + j)) * FP + k0 + lg * 8);
        }
#pragma unroll
        for (int fi = 0; fi < 5; ++fi)
#pragma unroll
            for (int ji = 0; ji < 4; ++ji)
                acc[fi][ji] = __builtin_amdgcn_mfma_f32_16x16x32_bf16(a[fi], bb[ji], acc[fi][ji], 0, 0, 0);
    }
#pragma unroll
    for (int fi = 0; fi < 5; ++fi)
#pragma unroll
        for (int ji = 0; ji < 4; ++ji)
#pragma unroll
            for (int r = 0; r < 4; ++r) {
                int f = (wave * 5 + fi) * 16 + lg * 4 + r;   // 0..319
                int j = j0 + ji * 16 + lr;                   // 0..4095
                int ft = f >> 4, floc = f & 15;
                int kt = j >> 6, jloc = j & 63;
                size_t base = (size_t)((b * 20 + ft) * 64 + kt) * YTILE;
                int byte = floc * 128 + (((jloc >> 3) * 16) ^ ((floc & 7) << 4)) + (jloc & 7) * 2;
                *(__bf16*)(Ytt + base + byte) = (__bf16)acc[fi][ji][r];
            }
}

// ---------------- K4 v5: out = d_i * (adj @ Yt) + bias ---------------------
// R8 mechanics, re-geometried to cut LDS-read volume 2.2x:
// 512 blocks x 128 thr (2 waves). Wave tile 64m x 80f (4 m-frags x 5 n-frags).
// Per step: stage 26 chunks (16 A + 10 B) = EXACTLY 13 gload_lds per wave ->
// uniform vmcnt(26) (t landed; t+1,t+2 in flight). Ring 3 x 26 KB = 78 KB ->
// 2 blocks/CU (desynced, overlap each other's barriers).
// Per wave-step: 18 ds_read_b128 -> 40 MFMA (read:MFMA = 0.45 vs R8's 1.2).
// bid = by*128 + b*32 + bx: by-siblings differ by 128 = 0 mod 8 -> same XCD,
// A re-reads served by L2.
__global__ __launch_bounds__(128) void k_gemm_pipe(const char* __restrict__ adjb,
                                                   const char* __restrict__ ytt,
                                                   const float* __restrict__ d,
                                                   const float* __restrict__ bias,
                                                   float* __restrict__ out) {
    __shared__ __align__(16) char smem[3 * STEP_B2];   // 78 KB
    const int bid = blockIdx.x;               // 0..511
    const int bx  = bid & 31;                 // 32 m-blocks of 128 rows
    const int b   = (bid >> 5) & 3;           // batch
    const int by  = bid >> 7;                 // 0..3 (80-f panel)
    const int w = threadIdx.x >> 6, lane = threadIdx.x & 63;
    const int lr = lane & 15, lg = lane >> 4;

    // --- staging plan: 26 chunks; wave w issues cids w*13 .. w*13+12 --------
    const char* gp[13];
    int st[13], lo[13];
#pragma unroll
    for (int g = 0; g < 13; ++g) {
        int cid = w * 13 + g;                 // 0..25
        if (cid < 16) {  // A: adjb tile (b*NMT + bx*2 + (cid>>3)), chunk cid&7
            gp[g] = adjb + (size_t)((b * NMT + bx * 2 + (cid >> 3)) * NKT) * TILE_BYTES
                    + (cid & 7) * 1024 + lane * 16;
            st[g] = TILE_BYTES;
            lo[g] = cid * 1024;
        } else {         // B: Ytt tile ft = by*5 + (cc>>1), half cc&1
            int cc = cid - 16;                // 0..9
            gp[g] = ytt + (size_t)((b * 20 + by * 5 + (cc >> 1)) * 64) * YTILE
                    + (cc & 1) * 1024 + lane * 16;
            st[g] = YTILE;
            lo[g] = 16384 + cc * 1024;
        }
    }

    // --- swizzled LDS read addresses ---------------------------------------
    uint32_t sb = (uint32_t)(uintptr_t)(__attribute__((address_space(3))) char*)smem;
    const int sw = (lr & 7) << 4;
    const uint32_t col0 = (uint32_t)((lg * 16) ^ sw);          // kh=0
    const uint32_t col1 = (uint32_t)(((4 + lg) * 16) ^ sw);    // kh=1
    uint32_t rowA[4];
#pragma unroll
    for (int mi = 0; mi < 4; ++mi)
        rowA[mi] = sb + w * 8192 + (mi * 16 + lr) * 128;       // wave w's tile
    uint32_t rowB[5];
#pragma unroll
    for (int nt = 0; nt < 5; ++nt) rowB[nt] = sb + 16384 + nt * YTILE + lr * 128;

    f32x4 acc[4][5] = {};
    uint32_t oc = 0, on = STEP_B2, ot = 2 * STEP_B2;

    // prologue: tiles 0,1 -> 26 outstanding per wave
#pragma unroll
    for (int g = 0; g < 13; ++g) gload_lds16(gp[g], smem + lo[g]);
#pragma unroll
    for (int g = 0; g < 13; ++g) gload_lds16(gp[g] + st[g], smem + STEP_B2 + lo[g]);

    for (int t = 0; t < NKT; ++t) {
        int ks = t + 2 > NKT - 1 ? NKT - 1 : t + 2;
        SB();
#pragma unroll
        for (int g = 0; g < 13; ++g)
            gload_lds16(gp[g] + (size_t)ks * st[g], smem + ot + lo[g]);
        SB();
        asm volatile("s_waitcnt vmcnt(26)");  // tile t complete; t+1,t+2 in flight
        SB();
        __builtin_amdgcn_s_barrier();         // all waves' tile-t chunks landed
        bf16x8 af[4][2], bf[5][2];
#pragma unroll
        for (int mi = 0; mi < 4; ++mi) {
            asm volatile("ds_read_b128 %0, %1" : "=v"(af[mi][0]) : "v"(oc + rowA[mi] + col0));
            asm volatile("ds_read_b128 %0, %1" : "=v"(af[mi][1]) : "v"(oc + rowA[mi] + col1));
        }
#pragma unroll
        for (int nt = 0; nt < 5; ++nt) {
            asm volatile("ds_read_b128 %0, %1" : "=v"(bf[nt][0]) : "v"(oc + rowB[nt] + col0));
            asm volatile("ds_read_b128 %0, %1" : "=v"(bf[nt][1]) : "v"(oc + rowB[nt] + col1));
        }
        asm volatile("s_waitcnt lgkmcnt(0)");
        SB();                                  // rule 18: fence MFMA below the wait
        __builtin_amdgcn_s_barrier();          // all waves done reading -> buf reusable
        __builtin_amdgcn_s_setprio(1);
#pragma unroll
        for (int kh = 0; kh < 2; ++kh)
#pragma unroll
            for (int mi = 0; mi < 4; ++mi)
#pragma unroll
                for (int nt = 0; nt < 5; ++nt)
                    acc[mi][nt] = __builtin_amdgcn_mfma_f32_16x16x32_bf16(af[mi][kh], bf[nt][kh], acc[mi][nt], 0, 0, 0);
        __builtin_amdgcn_s_setprio(0);
        SB();
        uint32_t tmp = oc; oc = on; on = ot; ot = tmp;   // rotate ring
    }

    // epilogue: scale by d_i, add bias, store (f < 300 only)
    const int rowb = bx * 128 + w * 64;
#pragma unroll
    for (int mi = 0; mi < 4; ++mi) {
        float di[4];
#pragma unroll
        for (int r = 0; r < 4; ++r)
            di[r] = d[b * N_ + rowb + mi * 16 + lg * 4 + r];
#pragma unroll
        for (int nt = 0; nt < 5; ++nt) {
            int f = by * 80 + nt * 16 + lr;
            if (f < FOUT) {
                float bv = bias[f];
#pragma unroll
                for (int r = 0; r < 4; ++r) {
                    int i = rowb + mi * 16 + lg * 4 + r;
                    out[((size_t)b * N_ + i) * FOUT + f] = di[r] * acc[mi][nt][r] + bv;
                }
            }
        }
    }
}

// ---------------- Fallback GEMM (fp32 adj direct; only if ws too small) ----
#define FB_LOAD(AV, BV, K0)                                                           \
    {                                                                                 \
        _Pragma("unroll")                                                             \
        for (int mi = 0; mi < 2; ++mi) {                                              \
            const float4* p = (const float4*)(adjf + (size_t)(rowbase + mi * 16 + lr) * N_ + (K0) + lg * 8); \
            float4 v0 = p[0], v1 = p[1];                                              \
            AV[mi][0] = (__bf16)v0.x; AV[mi][1] = (__bf16)v0.y;                       \
            AV[mi][2] = (__bf16)v0.z; AV[mi][3] = (__bf16)v0.w;                       \
            AV[mi][4] = (__bf16)v1.x; AV[mi][5] = (__bf16)v1.y;                       \
            AV[mi][6] = (__bf16)v1.z; AV[mi][7] = (__bf16)v1.w;                       \
        }                                                                             \
        _Pragma("unroll")                                                             \
        for (int nt = 0; nt < 10; ++nt) {                                             \
            int f = wn * 160 + nt * 16 + lr;                                          \
            BV[nt] = *(const bf16x8*)(Yb + (size_t)f * N_ + (K0) + lg * 8);           \
        }                                                                             \
    }
#define FB_MFMA(AV, BV)                                                               \
    {                                                                                 \
        _Pragma("unroll")                                                             \
        for (int mi = 0; mi < 2; ++mi)                                                \
            _Pragma("unroll")                                                         \
            for (int nt = 0; nt < 10; ++nt)                                           \
                acc[mi][nt] = __builtin_amdgcn_mfma_f32_16x16x32_bf16(AV[mi], BV[nt], acc[mi][nt], 0, 0, 0); \
    }

__global__ __launch_bounds__(256) void k_gemm_fb(const float* __restrict__ adj,
                                                 const __bf16* __restrict__ Yt,
                                                 const float* __restrict__ d,
                                                 const float* __restrict__ bias,
                                                 float* __restrict__ out) {
    int b    = blockIdx.y;
    int wave = threadIdx.x >> 6, lane = threadIdx.x & 63;
    int wm = wave & 1, wn = wave >> 1;
    int lr = lane & 15, lg = lane >> 4;
    int rowbase = blockIdx.x * 64 + wm * 32;
    const float*  adjf = adj + (size_t)b * N_ * N_;
    const __bf16* Yb   = Yt + (size_t)b * FP * N_;

    f32x4 acc[2][10] = {};
    bf16x8 aA[2], bA[10], aB[2], bB[10];

    FB_LOAD(aA, bA, 0)
    for (int k0 = 0; k0 < N_ - 64; k0 += 64) {
        FB_LOAD(aB, bB, k0 + 32)
        FB_MFMA(aA, bA)
        FB_LOAD(aA, bA, k0 + 64)
        FB_MFMA(aB, bB)
    }
    FB_LOAD(aB, bB, N_ - 32)
    FB_MFMA(aA, bA)
    FB_MFMA(aB, bB)

#pragma unroll
    for (int mi = 0; mi < 2; ++mi) {
        float di[4];
#pragma unroll
        for (int r = 0; r < 4; ++r)
            di[r] = d[b * N_ + rowbase + mi * 16 + lg * 4 + r];
#pragma unroll
        for (int nt = 0; nt < 10; ++nt) {
            int f = wn * 160 + nt * 16 + lr;
            if (f < FOUT) {
                float bv = bias[f];
#pragma unroll
                for (int r = 0; r < 4; ++r) {
                    int i = rowbase + mi * 16 + lg * 4 + r;
                    out[((size_t)b * N_ + i) * FOUT + f] = di[r] * acc[mi][nt][r] + bv;
                }
            }
        }
    }
}

extern "C" void kernel_launch(void* const* d_in, const int* in_sizes, int n_in,
                              void* d_out, int out_size, void* d_ws, size_t ws_size,
                              hipStream_t stream) {
    const float* text = (const float*)d_in[0];
    const float* adj  = (const float*)d_in[1];
    const float* W    = (const float*)d_in[2];
    const float* bias = (const float*)d_in[3];
    float* out = (float*)d_out;

    char* ws = (char*)d_ws;
    __bf16* Wt   = (__bf16*)(ws + WT_OFF);
    float*  dv   = (float*)(ws + D_OFF);
    __bf16* Tsc  = (__bf16*)(ws + TSC_OFF);
    char*   Ybuf = ws + YT_OFF;
    char*   adjb = ws + ADJB_OFF;

    bool big = ws_size >= (size_t)ADJB_OFF + ADJB_BYTES;

    k_wt<<<dim3((FP * FP + 255) / 256), dim3(256), 0, stream>>>(W, Wt);
    if (big)
        k_rowsum_cvt<<<dim3(NMT, B_), dim3(512), 0, stream>>>(adj, dv, adjb);
    else
        k_rowsum<<<dim3(B_ * N_ / 4), dim3(256), 0, stream>>>(adj, dv);
    k_tsc<<<dim3(B_ * N_ * FP / 256), dim3(256), 0, stream>>>(text, dv, Tsc);
    if (big) {
        k_y_t<<<dim3(N_ / 64, B_), dim3(256), 0, stream>>>(Wt, Tsc, Ybuf);
        k_gemm_pipe<<<dim3(512), dim3(128), 0, stream>>>(adjb, Ybuf, dv, bias, out);
    } else {
        k_y<<<dim3(N_ / 64, B_), dim3(256), 0, stream>>>(Wt, Tsc, (__bf16*)Ybuf);
        k_gemm_fb<<<dim3(N_ / 64, B_), dim3(256), 0, stream>>>(adj, (__bf16*)Ybuf, dv, bias, out);
    }
}

// Round 12
// 187.839 us; speedup vs baseline: 1.2526x; 1.0311x over previous
//
#include <hip/hip_runtime.h>
#include <hip/hip_bf16.h>

typedef __bf16 bf16x8 __attribute__((ext_vector_type(8)));
typedef __bf16 bf16x4 __attribute__((ext_vector_type(4)));
typedef float  f32x4  __attribute__((ext_vector_type(4)));

#define B_   4
#define N_   4096
#define FIN  300
#define FOUT 300
#define FP   320   // padded feature dim (multiple of 32)
#define MT   64    // adjb tile rows
#define KT   64    // adjb tile cols
#define NMT  (N_/MT)
#define NKT  (N_/KT)
#define TILE_BYTES (MT*KT*2)   // 8192
#define YTILE 2048             // Ytt tile: 16 f x 64 k bf16
#define STEP_B2 26624          // per-K-step LDS: A 16 KB + B 10 KB

// ws layout (bytes)
#define WT_OFF   0                    // Wt   bf16 [FP][FP]
#define D_OFF    (512*1024)           // d    fp32 [B_*N_]
#define TSC_OFF  (1024*1024)          // Tsc  bf16 [B_*N_][FP]
#define YT_OFF   (16*1024*1024)       // Yt / Ytt (tiled)  ~10.5 MB
#define ADJB_OFF (32*1024*1024)       // adjb bf16 tiled+swizzled [B_][NMT][NKT][8KB]
#define ADJB_BYTES ((size_t)B_ * N_ * N_ * 2)

#define SB() __builtin_amdgcn_sched_barrier(0)

__device__ __forceinline__ void gload_lds16(const void* g, void* l) {
    __builtin_amdgcn_global_load_lds((const __attribute__((address_space(1))) void*)g,
                                     (__attribute__((address_space(3))) void*)l, 16, 0, 0);
}

// ---------------- K0: Wt[f][k] = bf16(W[k][f]), zero-padded ----------------
__global__ void k_wt(const float* __restrict__ W, __bf16* __restrict__ Wt) {
    int t = blockIdx.x * 256 + threadIdx.x;
    if (t >= FP * FP) return;
    int f = t / FP, k = t - f * FP;
    float v = (f < FOUT && k < FIN) ? W[k * FOUT + f] : 0.0f;
    Wt[t] = (__bf16)v;
}

// ---------------- K1a: rowsum only (fallback path) -------------------------
__global__ void k_rowsum(const float* __restrict__ adj, float* __restrict__ d) {
    int row  = blockIdx.x * 4 + (threadIdx.x >> 6);
    int lane = threadIdx.x & 63;
    const float4* p = (const float4*)(adj + (size_t)row * N_);
    float s = 0.0f;
#pragma unroll
    for (int it = 0; it < 16; ++it) {
        float4 v = p[it * 64 + lane];
        s += v.x + v.y + v.z + v.w;
    }
#pragma unroll
    for (int off = 32; off; off >>= 1) s += __shfl_xor(s, off);
    if (lane == 0) d[row] = rsqrtf(s + 1.0f);
}

// ---------------- K1b v2: rowsum + tiled/swizzled bf16 copy, COALESCED -----
// (R10-verified.) Global tile layout: adjb[(b*NMT+mt)*NKT + kt] is 8 KB =
// rows [mloc][64 bf16]; 16-B chunk c of a row at byte mloc*128 + (c*16 ^
// ((mloc&7)<<4)).
__global__ __launch_bounds__(512) void k_rowsum_cvt(const float* __restrict__ adj,
                                                    float* __restrict__ d,
                                                    char* __restrict__ adjb) {
    __shared__ __align__(16) char lds[4 * TILE_BYTES];   // 32 KB
    const int mt = blockIdx.x, b = blockIdx.y;
    const int t = threadIdx.x, w = t >> 6, lane = t & 63;
    const int tloc = lane >> 4;                 // which of the 4 tiles in group
    const int chunk = (lane & 15) >> 1;         // 16-B chunk within row
    const int sub8  = (lane & 1) * 8;           // byte offset within chunk
    const size_t rowbase = (size_t)b * N_ + mt * 64;
    char* gbase = adjb + (size_t)((b * NMT + mt) * NKT) * TILE_BYTES;

    float psum[8] = {};
    for (int g = 0; g < 16; ++g) {
#pragma unroll
        for (int rr = 0; rr < 8; ++rr) {
            int r = w * 8 + rr;
            float4 v = *(const float4*)(adj + (rowbase + r) * N_ + g * 256 + lane * 4);
            psum[rr] += v.x + v.y + v.z + v.w;
            bf16x4 o;
            o[0] = (__bf16)v.x; o[1] = (__bf16)v.y; o[2] = (__bf16)v.z; o[3] = (__bf16)v.w;
            int byte = tloc * TILE_BYTES + r * 128 + ((chunk * 16) ^ ((r & 7) << 4)) + sub8;
            *(bf16x4*)(lds + byte) = o;
        }
        __syncthreads();
#pragma unroll
        for (int i = 0; i < 4; ++i) {
            int idx = i * 512 + t;              // 16-B unit 0..2047
            int tl = idx >> 9, off = (idx & 511) * 16;
            *(f32x4*)(gbase + (size_t)(g * 4 + tl) * TILE_BYTES + off) =
                *(const f32x4*)(lds + tl * TILE_BYTES + off);
        }
        __syncthreads();
    }
#pragma unroll
    for (int rr = 0; rr < 8; ++rr) {
        float s = psum[rr];
#pragma unroll
        for (int off = 32; off; off >>= 1) s += __shfl_xor(s, off);
        if (lane == 0) d[rowbase + w * 8 + rr] = rsqrtf(s + 1.0f);
    }
}

// ---------------- K2: Tsc[j][k] = bf16(d[j]*text[j][k]), K zero-padded -----
__global__ void k_tsc(const float* __restrict__ text, const float* __restrict__ d,
                      __bf16* __restrict__ Tsc) {
    int t = blockIdx.x * 256 + threadIdx.x;
    int j = t / FP;
    int k = t - j * FP;
    float v = 0.0f;
    if (k < FIN) v = d[j] * text[(size_t)j * FIN + k];
    Tsc[t] = (__bf16)v;
}

// ---------------- K3a: plain Yt (fallback): Yt[b][f][j] --------------------
__global__ __launch_bounds__(256) void k_y(const __bf16* __restrict__ Wt,
                                           const __bf16* __restrict__ Tsc,
                                           __bf16* __restrict__ Yt) {
    int b    = blockIdx.y;
    int j0   = blockIdx.x * 64;
    int wave = threadIdx.x >> 6, lane = threadIdx.x & 63;
    int lr = lane & 15, lg = lane >> 4;
    f32x4 acc[5][4] = {};
    for (int k0 = 0; k0 < FP; k0 += 32) {
        bf16x8 a[5], bb[4];
#pragma unroll
        for (int fi = 0; fi < 5; ++fi) {
            int f = (wave * 5 + fi) * 16 + lr;
            a[fi] = *(const bf16x8*)(Wt + (size_t)f * FP + k0 + lg * 8);
        }
#pragma unroll
        for (int ji = 0; ji < 4; ++ji) {
            int j = j0 + ji * 16 + lr;
            bb[ji] = *(const bf16x8*)(Tsc + ((size_t)(b * N_ + j)) * FP + k0 + lg * 8);
        }
#pragma unroll
        for (int fi = 0; fi < 5; ++fi)
#pragma unroll
            for (int ji = 0; ji < 4; ++ji)
                acc[fi][ji] = __builtin_amdgcn_mfma_f32_16x16x32_bf16(a[fi], bb[ji], acc[fi][ji], 0, 0, 0);
    }
#pragma unroll
    for (int fi = 0; fi < 5; ++fi)
#pragma unroll
        for (int ji = 0; ji < 4; ++ji)
#pragma unroll
            for (int r = 0; r < 4; ++r) {
                int f = (wave * 5 + fi) * 16 + lg * 4 + r;
                int j = j0 + ji * 16 + lr;
                Yt[((size_t)b * FP + f) * N_ + j] = (__bf16)acc[fi][ji][r];
            }
}

// ---------------- K3b: tiled+swizzled Ytt for the pipelined GEMM -----------
// Ytt tile (ft, kt): 2 KB = 16 f-rows x 64 k bf16, tile idx (b*20+ft)*64+kt.
// Within tile: row floc at byte floc*128; 16-B chunk c at byte
// (c*16 ^ ((floc&7)<<4)); elements (k&7) consecutive inside the chunk.
__global__ __launch_bounds__(256) void k_y_t(const __bf16* __restrict__ Wt,
                                             const __bf16* __restrict__ Tsc,
                                             char* __restrict__ Ytt) {
    int b    = blockIdx.y;
    int j0   = blockIdx.x * 64;
    int wave = threadIdx.x >> 6, lane = threadIdx.x & 63;
    int lr = lane & 15, lg = lane >> 4;
    f32x4 acc[5][4] = {};
    for (int k0 = 0; k0 < FP; k0 += 32) {
        bf16x8 a[5], bb[4];
#pragma unroll
        for (int fi = 0; fi < 5; ++fi) {
            int f = (wave * 5 + fi) * 16 + lr;
            a[fi] = *(const bf16x8*)(Wt + (size_t)f * FP + k0 + lg * 8);
        }
#pragma unroll
        for (int ji = 0; ji < 4; ++ji) {
            int j = j0 + ji * 16 + lr;
            bb[ji] = *(const bf16x8*)(Tsc + ((size_t)(b * N_ + j)) * FP + k0 + lg * 8);
        }
#pragma unroll
        for (int fi = 0; fi < 5; ++fi)
#pragma unroll
            for (int ji = 0; ji < 4; ++ji)
                acc[fi][ji] = __builtin_amdgcn_mfma_f32_16x16x32_bf16(a[fi], bb[ji], acc[fi][ji], 0, 0, 0);
    }
#pragma unroll
    for (int fi = 0; fi < 5; ++fi)
#pragma unroll
        for (int ji = 0; ji < 4; ++ji)
#pragma unroll
            for (int r = 0; r < 4; ++r) {
                int f = (wave * 5 + fi) * 16 + lg * 4 + r;   // 0..319
                int j = j0 + ji * 16 + lr;                   // 0..4095
                int ft = f >> 4, floc = f & 15;
                int kt = j >> 6, jloc = j & 63;
                size_t base = (size_t)((b * 20 + ft) * 64 + kt) * YTILE;
                int byte = floc * 128 + (((jloc >> 3) * 16) ^ ((floc & 7) << 4)) + (jloc & 7) * 2;
                *(__bf16*)(Ytt + base + byte) = (__bf16)acc[fi][ji][r];
            }
}

// ---------------- K4 v6: out = d_i * (adj @ Yt) + bias ---------------------
// R11 LDS budget, R8 TLP: 512 blocks x 256 thr (4 waves, 4m x 1n).
// Wave tile 32m x 80f (2 m-frags x 5 n-frags). BM=128, BN=80, BK=64.
// Step 26 KB (A 16 + B 10), ring 3 = 78 KB -> 2 blocks/CU = 8 waves/CU =
// 2 waves/SIMD (the R11 fix: TLP to hide each wave's serial step chain).
// Staging: 28 chunks (26 real + 2 benign duplicates) = EXACTLY 7 gload_lds
// per wave -> uniform vmcnt(14) (tile t landed; t+1,t+2 in flight).
// Per wave-step: 14 ds_read_b128 -> 20 MFMA (ratio 0.7).
// bid = by*128 + b*32 + bx: by-siblings differ by 128 = 0 mod 8 -> same XCD.
__global__ __launch_bounds__(256) void k_gemm_pipe(const char* __restrict__ adjb,
                                                   const char* __restrict__ ytt,
                                                   const float* __restrict__ d,
                                                   const float* __restrict__ bias,
                                                   float* __restrict__ out) {
    __shared__ __align__(16) char smem[3 * STEP_B2];   // 78 KB -> 2 blocks/CU
    const int bid = blockIdx.x;               // 0..511
    const int bx  = bid & 31;                 // 32 m-blocks of 128 rows
    const int b   = (bid >> 5) & 3;           // batch
    const int by  = bid >> 7;                 // 0..3 (80-f panel)
    const int w = threadIdx.x >> 6, lane = threadIdx.x & 63;
    const int lr = lane & 15, lg = lane >> 4;

    // --- staging plan: 26 real chunks (16 A + 10 B); wave w issues cids
    // w*7 .. w*7+6; cid >= 26 wraps to 0,1 (same src+dst as wave 0 -> benign).
    const char* gp[7];
    int st[7], lo[7];
#pragma unroll
    for (int g = 0; g < 7; ++g) {
        int cid = w * 7 + g; if (cid >= 26) cid -= 26;
        if (cid < 16) {  // A: adjb tile (b*NMT + bx*2 + (cid>>3)), chunk cid&7
            gp[g] = adjb + (size_t)((b * NMT + bx * 2 + (cid >> 3)) * NKT) * TILE_BYTES
                    + (cid & 7) * 1024 + lane * 16;
            st[g] = TILE_BYTES;
            lo[g] = cid * 1024;
        } else {         // B: Ytt tile ft = by*5 + (cc>>1), half cc&1
            int cc = cid - 16;                // 0..9
            gp[g] = ytt + (size_t)((b * 20 + by * 5 + (cc >> 1)) * 64) * YTILE
                    + (cc & 1) * 1024 + lane * 16;
            st[g] = YTILE;
            lo[g] = 16384 + cc * 1024;
        }
    }

    // --- swizzled LDS read addresses ---------------------------------------
    // A LDS image: rows 0..127 of the block at byte row*128 (tile0 rows 0-63,
    // tile1 rows 64-127), chunk-swizzled by ((row&7)<<4). Wave w owns rows
    // w*32 + mi*16 + lr  (w*32, mi*16 are multiples of 8 -> swizzle = lr&7).
    uint32_t sb = (uint32_t)(uintptr_t)(__attribute__((address_space(3))) char*)smem;
    const int sw = (lr & 7) << 4;
    const uint32_t col0 = (uint32_t)((lg * 16) ^ sw);          // kh=0
    const uint32_t col1 = (uint32_t)(((4 + lg) * 16) ^ sw);    // kh=1
    uint32_t rowA[2];
#pragma unroll
    for (int mi = 0; mi < 2; ++mi)
        rowA[mi] = sb + (w * 32 + mi * 16 + lr) * 128;
    uint32_t rowB[5];
#pragma unroll
    for (int nt = 0; nt < 5; ++nt) rowB[nt] = sb + 16384 + nt * YTILE + lr * 128;

    f32x4 acc[2][5] = {};
    uint32_t oc = 0, on = STEP_B2, ot = 2 * STEP_B2;

    // prologue: tiles 0,1 -> 14 outstanding per wave
#pragma unroll
    for (int g = 0; g < 7; ++g) gload_lds16(gp[g], smem + lo[g]);
#pragma unroll
    for (int g = 0; g < 7; ++g) gload_lds16(gp[g] + st[g], smem + STEP_B2 + lo[g]);

    for (int t = 0; t < NKT; ++t) {
        int ks = t + 2 > NKT - 1 ? NKT - 1 : t + 2;
        SB();
#pragma unroll
        for (int g = 0; g < 7; ++g)
            gload_lds16(gp[g] + (size_t)ks * st[g], smem + ot + lo[g]);
        SB();
        asm volatile("s_waitcnt vmcnt(14)");  // tile t complete; t+1,t+2 in flight
        SB();
        __builtin_amdgcn_s_barrier();         // all waves' tile-t chunks landed
        bf16x8 af[2][2], bf[5][2];
#pragma unroll
        for (int mi = 0; mi < 2; ++mi) {
            asm volatile("ds_read_b128 %0, %1" : "=v"(af[mi][0]) : "v"(oc + rowA[mi] + col0));
            asm volatile("ds_read_b128 %0, %1" : "=v"(af[mi][1]) : "v"(oc + rowA[mi] + col1));
        }
#pragma unroll
        for (int nt = 0; nt < 5; ++nt) {
            asm volatile("ds_read_b128 %0, %1" : "=v"(bf[nt][0]) : "v"(oc + rowB[nt] + col0));
            asm volatile("ds_read_b128 %0, %1" : "=v"(bf[nt][1]) : "v"(oc + rowB[nt] + col1));
        }
        asm volatile("s_waitcnt lgkmcnt(0)");
        SB();                                  // rule 18: fence MFMA below the wait
        __builtin_amdgcn_s_barrier();          // all waves done reading -> buf reusable
        __builtin_amdgcn_s_setprio(1);
#pragma unroll
        for (int kh = 0; kh < 2; ++kh)
#pragma unroll
            for (int mi = 0; mi < 2; ++mi)
#pragma unroll
                for (int nt = 0; nt < 5; ++nt)
                    acc[mi][nt] = __builtin_amdgcn_mfma_f32_16x16x32_bf16(af[mi][kh], bf[nt][kh], acc[mi][nt], 0, 0, 0);
        __builtin_amdgcn_s_setprio(0);
        SB();
        uint32_t tmp = oc; oc = on; on = ot; ot = tmp;   // rotate ring
    }

    // epilogue: scale by d_i, add bias, store (f < 300 only)
    const int rowb = bx * 128 + w * 32;
#pragma unroll
    for (int mi = 0; mi < 2; ++mi) {
        float di[4];
#pragma unroll
        for (int r = 0; r < 4; ++r)
            di[r] = d[b * N_ + rowb + mi * 16 + lg * 4 + r];
#pragma unroll
        for (int nt = 0; nt < 5; ++nt) {
            int f = by * 80 + nt * 16 + lr;
            if (f < FOUT) {
                float bv = bias[f];
#pragma unroll
                for (int r = 0; r < 4; ++r) {
                    int i = rowb + mi * 16 + lg * 4 + r;
                    out[((size_t)b * N_ + i) * FOUT + f] = di[r] * acc[mi][nt][r] + bv;
                }
            }
        }
    }
}

// ---------------- Fallback GEMM (fp32 adj direct; only if ws too small) ----
#define FB_LOAD(AV, BV, K0)                                                           \
    {                                                                                 \
        _Pragma("unroll")                                                             \
        for (int mi = 0; mi < 2; ++mi) {                                              \
            const float4* p = (const float4*)(adjf + (size_t)(rowbase + mi * 16 + lr) * N_ + (K0) + lg * 8); \
            float4 v0 = p[0], v1 = p[1];                                              \
            AV[mi][0] = (__bf16)v0.x; AV[mi][1] = (__bf16)v0.y;                       \
            AV[mi][2] = (__bf16)v0.z; AV[mi][3] = (__bf16)v0.w;                       \
            AV[mi][4] = (__bf16)v1.x; AV[mi][5] = (__bf16)v1.y;                       \
            AV[mi][6] = (__bf16)v1.z; AV[mi][7] = (__bf16)v1.w;                       \
        }                                                                             \
        _Pragma("unroll")                                                             \
        for (int nt = 0; nt < 10; ++nt) {                                             \
            int f = wn * 160 + nt * 16 + lr;                                          \
            BV[nt] = *(const bf16x8*)(Yb + (size_t)f * N_ + (K0) + lg * 8);           \
        }                                                                             \
    }
#define FB_MFMA(AV, BV)                                                               \
    {                                                                                 \
        _Pragma("unroll")                                                             \
        for (int mi = 0; mi < 2; ++mi)                                                \
            _Pragma("unroll")                                                         \
            for (int nt = 0; nt < 10; ++nt)                                           \
                acc[mi][nt] = __builtin_amdgcn_mfma_f32_16x16x32_bf16(AV[mi], BV[nt], acc[mi][nt], 0, 0, 0); \
    }

__global__ __launch_bounds__(256) void k_gemm_fb(const float* __restrict__ adj,
                                                 const __bf16* __restrict__ Yt,
                                                 const float* __restrict__ d,
                                                 const float* __restrict__ bias,
                                                 float* __restrict__ out) {
    int b    = blockIdx.y;
    int wave = threadIdx.x >> 6, lane = threadIdx.x & 63;
    int wm = wave & 1, wn = wave >> 1;
    int lr = lane & 15, lg = lane >> 4;
    int rowbase = blockIdx.x * 64 + wm * 32;
    const float*  adjf = adj + (size_t)b * N_ * N_;
    const __bf16* Yb   = Yt + (size_t)b * FP * N_;

    f32x4 acc[2][10] = {};
    bf16x8 aA[2], bA[10], aB[2], bB[10];

    FB_LOAD(aA, bA, 0)
    for (int k0 = 0; k0 < N_ - 64; k0 += 64) {
        FB_LOAD(aB, bB, k0 + 32)
        FB_MFMA(aA, bA)
        FB_LOAD(aA, bA, k0 + 64)
        FB_MFMA(aB, bB)
    }
    FB_LOAD(aB, bB, N_ - 32)
    FB_MFMA(aA, bA)
    FB_MFMA(aB, bB)

#pragma unroll
    for (int mi = 0; mi < 2; ++mi) {
        float di[4];
#pragma unroll
        for (int r = 0; r < 4; ++r)
            di[r] = d[b * N_ + rowbase + mi * 16 + lg * 4 + r];
#pragma unroll
        for (int nt = 0; nt < 10; ++nt) {
            int f = wn * 160 + nt * 16 + lr;
            if (f < FOUT) {
                float bv = bias[f];
#pragma unroll
                for (int r = 0; r < 4; ++r) {
                    int i = rowbase + mi * 16 + lg * 4 + r;
                    out[((size_t)b * N_ + i) * FOUT + f] = di[r] * acc[mi][nt][r] + bv;
                }
            }
        }
    }
}

extern "C" void kernel_launch(void* const* d_in, const int* in_sizes, int n_in,
                              void* d_out, int out_size, void* d_ws, size_t ws_size,
                              hipStream_t stream) {
    const float* text = (const float*)d_in[0];
    const float* adj  = (const float*)d_in[1];
    const float* W    = (const float*)d_in[2];
    const float* bias = (const float*)d_in[3];
    float* out = (float*)d_out;

    char* ws = (char*)d_ws;
    __bf16* Wt   = (__bf16*)(ws + WT_OFF);
    float*  dv   = (float*)(ws + D_OFF);
    __bf16* Tsc  = (__bf16*)(ws + TSC_OFF);
    char*   Ybuf = ws + YT_OFF;
    char*   adjb = ws + ADJB_OFF;

    bool big = ws_size >= (size_t)ADJB_OFF + ADJB_BYTES;

    k_wt<<<dim3((FP * FP + 255) / 256), dim3(256), 0, stream>>>(W, Wt);
    if (big)
        k_rowsum_cvt<<<dim3(NMT, B_), dim3(512), 0, stream>>>(adj, dv, adjb);
    else
        k_rowsum<<<dim3(B_ * N_ / 4), dim3(256), 0, stream>>>(adj, dv);
    k_tsc<<<dim3(B_ * N_ * FP / 256), dim3(256), 0, stream>>>(text, dv, Tsc);
    if (big) {
        k_y_t<<<dim3(N_ / 64, B_), dim3(256), 0, stream>>>(Wt, Tsc, Ybuf);
        k_gemm_pipe<<<dim3(512), dim3(256), 0, stream>>>(adjb, Ybuf, dv, bias, out);
    } else {
        k_y<<<dim3(N_ / 64, B_), dim3(256), 0, stream>>>(Wt, Tsc, (__bf16*)Ybuf);
        k_gemm_fb<<<dim3(N_ / 64, B_), dim3(256), 0, stream>>>(adj, (__bf16*)Ybuf, dv, bias, out);
    }
}